// Round 2
// baseline (147.957 us; speedup 1.0000x reference)
//
#include <hip/hip_runtime.h>
#include <hip/hip_bf16.h>

#define B_ 32
#define T_ 4096
#define H_ 512
#define TILE_T 4
#define M_TILE 128   // TILE_T * B_
#define BK 32
#define KSTEPS 16    // H_ / BK
#define APAD 40      // lds_a row stride (elems): 32 used + 8 pad -> 2-way banks
#define NTHREADS 512

typedef __attribute__((ext_vector_type(8))) short short8;
typedef __attribute__((ext_vector_type(8))) __bf16 bf16x8;
typedef __attribute__((ext_vector_type(4))) float f32x4;

__device__ __forceinline__ short f2bf(float f) {
    unsigned u = __builtin_bit_cast(unsigned, f);
    u = (u + 0x7fffu + ((u >> 16) & 1u)) >> 16;
    return (short)u;
}

// ---------------- prep: W2 -> bf16, chunk-swizzled per K-step ----------------
// layout w2p[s][h][kp], kp = c'*8 + j, where source chunk c = c' ^ ((h>>1)&3)
// i.e. w2p[s][h][kp] = bf16( W[h][512 + s*32 + ((kp>>3) ^ ((h>>1)&3))*8 + (kp&7)] )
__global__ void prep_w2(const float* __restrict__ W, short* __restrict__ w2p) {
    int idx = blockIdx.x * 256 + threadIdx.x;   // 0 .. 262143
    int kp = idx & 31;
    int h  = (idx >> 5) & 511;
    int s  = idx >> 14;
    int k  = ((kp >> 3) ^ ((h >> 1) & 3)) * 8 + (kp & 7);
    w2p[idx] = f2bf(W[h * (2 * H_) + H_ + s * BK + k]);
}

// ---------------- prep: hid_proj[b][h] = hidden[b,:]*W1[h,:] + bias[h] (f32 exact) ----
__global__ void prep_hid(const float* __restrict__ hidden,
                         const float* __restrict__ W,
                         const float* __restrict__ bias,
                         float* __restrict__ hidproj) {
    __shared__ float hrow[H_];
    int b = blockIdx.y;
    int h = blockIdx.x * 128 + threadIdx.x;
    for (int i = threadIdx.x; i < H_; i += 128) hrow[i] = hidden[b * H_ + i];
    __syncthreads();
    const float* wr = W + (size_t)h * (2 * H_);
    float acc = bias[h];
#pragma unroll 4
    for (int k = 0; k < H_; k += 4) {
        acc += hrow[k]     * wr[k];
        acc += hrow[k + 1] * wr[k + 1];
        acc += hrow[k + 2] * wr[k + 2];
        acc += hrow[k + 3] * wr[k + 3];
    }
    hidproj[b * H_ + h] = acc;
}

// ---------------- main fused kernel: 2-phase pipelined ----------------
// grid: T_/TILE_T blocks; block: 512 threads (8 waves), wave w owns h in [w*64, w*64+64)
__global__ __launch_bounds__(NTHREADS, 2)
void attn_main(const float* __restrict__ enc,      // [T][B][H] f32
               const float* __restrict__ hidproj,  // [B][H] f32
               const short* __restrict__ w2p,      // [KSTEPS][H][BK] bf16 chunk-swizzled
               const float* __restrict__ vvec,     // [H]
               float* __restrict__ out)            // [B][T]
{
    __shared__ __align__(16) short lds_w[2][H_ * BK];      // 2 x 32 KB
    __shared__ __align__(16) short lds_a[2][M_TILE * APAD]; // 2 x 10 KB

    const int tid  = threadIdx.x;
    const int lane = tid & 63;
    const int wid  = tid >> 6;
    const int t0   = blockIdx.x * TILE_T;
    const int n0   = wid * 64;
    const int lo   = lane & 15;
    const int hi4  = lane >> 4;
    const int wsw  = (lo >> 1) & 3;        // W chunk swizzle for this lane's rows
    const int wchunk = (hi4 ^ wsw) * 8;    // swizzled k-chunk offset in lds_w row

    f32x4 acc[8][4];
#pragma unroll
    for (int i = 0; i < 8; ++i)
#pragma unroll
        for (int j = 0; j < 4; ++j) acc[i][j] = f32x4{0.f, 0.f, 0.f, 0.f};

    // A staging: thread -> (row = tid>>2 of 128, kc = tid&3 of 4 chunks of 8 f32)
    const int arow = tid >> 2;
    const int akc  = tid & 3;
    const float* asrc_base = enc + (size_t)(t0 * B_ + arow) * H_ + akc * 8;

    // ---- prologue: W(0) -> lds_w[0], A(0) -> regs -> lds_a[0] ----
    {
        const short* wsrc = w2p;
#pragma unroll
        for (int r = 0; r < 4; ++r) {
            __builtin_amdgcn_global_load_lds(
                (const __attribute__((address_space(1))) void*)(wsrc + (r * 512 + tid) * 8),
                (__attribute__((address_space(3))) void*)(&lds_w[0][(r * 512 + wid * 64) * 8]),
                16, 0, 0);
        }
        f32x4 x0 = *(const f32x4*)(asrc_base);
        f32x4 x1 = *(const f32x4*)(asrc_base + 4);
        short8 pk;
        pk[0] = f2bf(x0[0]); pk[1] = f2bf(x0[1]); pk[2] = f2bf(x0[2]); pk[3] = f2bf(x0[3]);
        pk[4] = f2bf(x1[0]); pk[5] = f2bf(x1[1]); pk[6] = f2bf(x1[2]); pk[7] = f2bf(x1[3]);
        *(short8*)&lds_a[0][arow * APAD + akc * 8] = pk;
    }

    // ---- main loop: one barrier per kstep, counted vmcnt ----
    for (int kk = 0; kk < KSTEPS; ++kk) {
        const int cur = kk & 1;
        // entry: A(kk) ds_writes visible; all waves done reading buffers cur^1
        asm volatile("s_waitcnt lgkmcnt(0)" ::: "memory");
        __builtin_amdgcn_s_barrier();

        f32x4 x0, x1;
        if (kk < KSTEPS - 1) {
            // issue prefetch of kstep kk+1: 4 global_load_lds + 2 f32x4 loads
            const short* wsrc = w2p + (size_t)(kk + 1) * (H_ * BK);
            short* wdst = &lds_w[cur ^ 1][0];
#pragma unroll
            for (int r = 0; r < 4; ++r) {
                __builtin_amdgcn_global_load_lds(
                    (const __attribute__((address_space(1))) void*)(wsrc + (r * 512 + tid) * 8),
                    (__attribute__((address_space(3))) void*)(wdst + (r * 512 + wid * 64) * 8),
                    16, 0, 0);
            }
            const float* asrc = asrc_base + (kk + 1) * BK;
            x0 = *(const f32x4*)(asrc);
            x1 = *(const f32x4*)(asrc + 4);
            // wait W(kk) landed: 6 ops (4 W(kk+1) + 2 A(kk+1)) may remain in flight
            asm volatile("s_waitcnt vmcnt(6)" ::: "memory");
        } else {
            asm volatile("s_waitcnt vmcnt(0)" ::: "memory");
        }

        // ---- compute kstep kk from buffers [cur] ----
        const short* __restrict__ wb = &lds_w[cur][0];
        const short* __restrict__ ab = &lds_a[cur][0];
        bf16x8 bfrag[4];
#pragma unroll
        for (int ni = 0; ni < 4; ++ni) {
            int hrow = n0 + ni * 16 + lo;
            bfrag[ni] = *(const bf16x8*)&wb[hrow * BK + wchunk];
        }
#pragma unroll
        for (int mi = 0; mi < 8; ++mi) {
            bf16x8 afrag = *(const bf16x8*)&ab[(mi * 16 + lo) * APAD + hi4 * 8];
#pragma unroll
            for (int ni = 0; ni < 4; ++ni)
                acc[mi][ni] = __builtin_amdgcn_mfma_f32_16x16x32_bf16(
                    afrag, bfrag[ni], acc[mi][ni], 0, 0, 0);
        }

        if (kk < KSTEPS - 1) {
            // cvt + write A(kk+1) into lds_a[cur^1] (safe: readers of cur^1 done pre-barrier)
            short8 pk;
            pk[0] = f2bf(x0[0]); pk[1] = f2bf(x0[1]); pk[2] = f2bf(x0[2]); pk[3] = f2bf(x0[3]);
            pk[4] = f2bf(x1[0]); pk[5] = f2bf(x1[1]); pk[6] = f2bf(x1[2]); pk[7] = f2bf(x1[3]);
            *(short8*)&lds_a[cur ^ 1][arow * APAD + akc * 8] = pk;
        }
    }

    // ---- epilogue ----
    {
        float hp[2][4][4];
#pragma unroll
        for (int par = 0; par < 2; ++par)
#pragma unroll
            for (int j = 0; j < 4; ++j) {
                int b = par * 16 + hi4 * 4 + j;
#pragma unroll
                for (int ni = 0; ni < 4; ++ni)
                    hp[par][j][ni] = hidproj[b * H_ + n0 + ni * 16 + lo];
            }
#pragma unroll
        for (int mi = 0; mi < 8; ++mi)
#pragma unroll
            for (int ni = 0; ni < 4; ++ni)
#pragma unroll
                for (int j = 0; j < 4; ++j)
                    acc[mi][ni][j] += hp[mi & 1][j][ni];
    }

    float vh[4];
#pragma unroll
    for (int ni = 0; ni < 4; ++ni) vh[ni] = vvec[n0 + ni * 16 + lo];

    float scp[8][4];  // [mi][j] partial scores (summed over this lane's 4 h)
#pragma unroll
    for (int tl = 0; tl < 4; ++tl) {
        const int m0 = tl * 2, m1 = tl * 2 + 1;
#pragma unroll
        for (int ni = 0; ni < 4; ++ni) {
            float mx = -1e30f;
#pragma unroll
            for (int j = 0; j < 4; ++j) {
                mx = fmaxf(mx, acc[m0][ni][j]);
                mx = fmaxf(mx, acc[m1][ni][j]);
            }
            mx = fmaxf(mx, __shfl_xor(mx, 16));
            mx = fmaxf(mx, __shfl_xor(mx, 32));
            float e0[4], e1[4];
            float sum = 0.f;
#pragma unroll
            for (int j = 0; j < 4; ++j) {
                e0[j] = __expf(acc[m0][ni][j] - mx);
                e1[j] = __expf(acc[m1][ni][j] - mx);
                sum += e0[j] + e1[j];
            }
            sum += __shfl_xor(sum, 16);
            sum += __shfl_xor(sum, 32);
            float rs = vh[ni] / sum;  // fold v[h] and 1/denom
#pragma unroll
            for (int j = 0; j < 4; ++j) {
                if (ni == 0) { scp[m0][j] = e0[j] * rs; scp[m1][j] = e1[j] * rs; }
                else         { scp[m0][j] += e0[j] * rs; scp[m1][j] += e1[j] * rs; }
            }
        }
    }

    // reduce over the 16 lanes (lo) holding different h for the same M row
#pragma unroll
    for (int mi = 0; mi < 8; ++mi)
#pragma unroll
        for (int j = 0; j < 4; ++j) {
            float x = scp[mi][j];
            x += __shfl_xor(x, 1);
            x += __shfl_xor(x, 2);
            x += __shfl_xor(x, 4);
            x += __shfl_xor(x, 8);
            scp[mi][j] = x;
        }

    // cross-wave reduce via LDS (reuse lds_a; all MFMA reads long done, but fence anyway)
    __syncthreads();
    float* red = (float*)&lds_a[0][0];  // [8][128] = 4 KB
    if (lo == 0) {
#pragma unroll
        for (int mi = 0; mi < 8; ++mi)
#pragma unroll
            for (int j = 0; j < 4; ++j)
                red[wid * 128 + mi * 16 + hi4 * 4 + j] = scp[mi][j];
    }
    __syncthreads();
    if (tid < 128) {
        float s = 0.f;
#pragma unroll
        for (int w = 0; w < 8; ++w) s += red[w * 128 + tid];
        int b  = tid & 31;
        int tl = tid >> 5;
        out[(size_t)b * T_ + (t0 + tl)] = fmaxf(s, 0.f);
    }
}

extern "C" void kernel_launch(void* const* d_in, const int* in_sizes, int n_in,
                              void* d_out, int out_size, void* d_ws, size_t ws_size,
                              hipStream_t stream) {
    const float* hidden = (const float*)d_in[0];
    const float* enc    = (const float*)d_in[1];
    const float* W      = (const float*)d_in[2];
    const float* bias   = (const float*)d_in[3];
    const float* v      = (const float*)d_in[4];
    float* out = (float*)d_out;

    float* hidproj = (float*)d_ws;                    // 64 KB
    short* w2p     = (short*)((char*)d_ws + 65536);   // 512 KB

    prep_w2<<<1024, 256, 0, stream>>>(W, w2p);
    prep_hid<<<dim3(4, 32), 128, 0, stream>>>(hidden, W, bias, hidproj);
    attn_main<<<T_ / TILE_T, NTHREADS, 0, stream>>>(enc, hidproj, w2p, v, out);
}

// Round 3
// 140.802 us; speedup vs baseline: 1.0508x; 1.0508x over previous
//
#include <hip/hip_runtime.h>
#include <hip/hip_bf16.h>

#define B_ 32
#define T_ 4096
#define H_ 512
#define TILE_T 4
#define M_TILE 128   // TILE_T * B_
#define BK 64
#define KSTEPS 8     // H_ / BK
#define NTHREADS 512

typedef __attribute__((ext_vector_type(8))) short short8;
typedef __attribute__((ext_vector_type(8))) __bf16 bf16x8;
typedef __attribute__((ext_vector_type(4))) float f32x4;

__device__ __forceinline__ short f2bf(float f) {
    unsigned u = __builtin_bit_cast(unsigned, f);
    u = (u + 0x7fffu + ((u >> 16) & 1u)) >> 16;
    return (short)u;
}

// ---------------- prep: W2 -> bf16, per-kstep, chunk^(h&7) swizzled ----------------
// w2p flat [s][h][kp], kp = c'*8 + j with source chunk c = c' ^ (h&7)
__global__ void prep_w2(const float* __restrict__ W, short* __restrict__ w2p) {
    int idx = blockIdx.x * 256 + threadIdx.x;   // 0 .. 262143
    int kp = idx & 63;
    int h  = (idx >> 6) & 511;
    int s  = idx >> 15;
    int k  = s * BK + (((kp >> 3) ^ (h & 7)) << 3) + (kp & 7);
    w2p[idx] = f2bf(W[h * (2 * H_) + H_ + k]);
}

// ---------------- prep: hid_proj[b][h] = hidden[b,:]*W1[h,:] + bias[h] (f32 exact) ----
__global__ void prep_hid(const float* __restrict__ hidden,
                         const float* __restrict__ W,
                         const float* __restrict__ bias,
                         float* __restrict__ hidproj) {
    __shared__ float hrow[H_];
    int b = blockIdx.y;
    int h = blockIdx.x * 128 + threadIdx.x;
    for (int i = threadIdx.x; i < H_; i += 128) hrow[i] = hidden[b * H_ + i];
    __syncthreads();
    const float* wr = W + (size_t)h * (2 * H_);
    float acc = bias[h];
#pragma unroll 4
    for (int k = 0; k < H_; k += 4) {
        acc += hrow[k]     * wr[k];
        acc += hrow[k + 1] * wr[k + 1];
        acc += hrow[k + 2] * wr[k + 2];
        acc += hrow[k + 3] * wr[k + 3];
    }
    hidproj[b * H_ + h] = acc;
}

// ---------------- main fused kernel: 4-phase-per-K-tile deep pipeline ----------------
__global__ __launch_bounds__(NTHREADS, 2)
void attn_main(const float* __restrict__ enc,      // [T][B][H] f32
               const float* __restrict__ hidproj,  // [B][H] f32
               const short* __restrict__ w2p,      // [KSTEPS][H][BK] bf16 swizzled
               const float* __restrict__ vvec,     // [H]
               float* __restrict__ out)            // [B][T]
{
    __shared__ __align__(16) short lds_w[2][H_ * BK];     // 2 x 64 KB
    __shared__ __align__(16) short lds_a[2][M_TILE * BK]; // 2 x 16 KB  (total 160 KB)

    const int tid  = threadIdx.x;
    const int lane = tid & 63;
    const int wid  = tid >> 6;
    const int t0   = blockIdx.x * TILE_T;
    const int n0   = wid * 64;
    const int lo   = lane & 15;
    const int hi4  = lane >> 4;

    f32x4 acc[8][4];
#pragma unroll
    for (int i = 0; i < 8; ++i)
#pragma unroll
        for (int j = 0; j < 4; ++j) acc[i][j] = f32x4{0.f, 0.f, 0.f, 0.f};

    // A staging map: thread -> row (0..127), akc (0..3; 16 f32 each)
    const int arow = tid >> 2;
    const int akc  = tid & 3;
    const float* abase = enc + (size_t)(t0 * B_ + arow) * H_ + akc * 16;

    // ---- prologue: stage tile 0 into buffers [0] ----
    {
        const float* s = abase;
        f32x4 x0 = *(const f32x4*)(s);
        f32x4 x1 = *(const f32x4*)(s + 4);
        f32x4 x2 = *(const f32x4*)(s + 8);
        f32x4 x3 = *(const f32x4*)(s + 12);
#pragma unroll
        for (int r = 0; r < 8; ++r) {
            __builtin_amdgcn_global_load_lds(
                (const __attribute__((address_space(1))) void*)(w2p + r * 4096 + tid * 8),
                (__attribute__((address_space(3))) void*)(&lds_w[0][r * 4096 + wid * 512]),
                16, 0, 0);
        }
        short8 p0, p1;
        p0[0]=f2bf(x0[0]); p0[1]=f2bf(x0[1]); p0[2]=f2bf(x0[2]); p0[3]=f2bf(x0[3]);
        p0[4]=f2bf(x1[0]); p0[5]=f2bf(x1[1]); p0[6]=f2bf(x1[2]); p0[7]=f2bf(x1[3]);
        p1[0]=f2bf(x2[0]); p1[1]=f2bf(x2[1]); p1[2]=f2bf(x2[2]); p1[3]=f2bf(x2[3]);
        p1[4]=f2bf(x3[0]); p1[5]=f2bf(x3[1]); p1[6]=f2bf(x3[2]); p1[7]=f2bf(x3[3]);
        *(short8*)&lds_a[0][arow * BK + (((2 * akc)     ^ (arow & 7)) << 3)] = p0;
        *(short8*)&lds_a[0][arow * BK + (((2 * akc + 1) ^ (arow & 7)) << 3)] = p1;
        __syncthreads();   // drains vmcnt(0) + lgkmcnt(0) + barrier
    }

#define PHASE_MFMA(AF, BF, MIBASE)                                              \
    __builtin_amdgcn_s_barrier();                                               \
    asm volatile("s_waitcnt lgkmcnt(0)" ::: "memory");                          \
    __builtin_amdgcn_sched_barrier(0);                                          \
    __builtin_amdgcn_s_setprio(1);                                              \
    _Pragma("unroll")                                                           \
    for (int mi = 0; mi < 4; ++mi)                                              \
        _Pragma("unroll")                                                       \
        for (int ni = 0; ni < 4; ++ni)                                          \
            acc[(MIBASE) + mi][ni] = __builtin_amdgcn_mfma_f32_16x16x32_bf16(   \
                AF[mi], BF[ni], acc[(MIBASE) + mi][ni], 0, 0, 0);               \
    __builtin_amdgcn_s_setprio(0);                                              \
    __builtin_amdgcn_sched_barrier(0);

    for (int kk = 0; kk < KSTEPS; ++kk) {
        const int cur = kk & 1;
        const int nx  = kk + 1;
        const bool pf = nx < KSTEPS;
        const short* __restrict__ wb = &lds_w[cur][0];
        const short* __restrict__ ab = &lds_a[cur][0];
        short* __restrict__ wdst = &lds_w[cur ^ 1][0];
        short* __restrict__ adst = &lds_a[cur ^ 1][0];
        const short* wsrc = w2p + (size_t)nx * (H_ * BK);
        const float* asrc = abase + (size_t)nx * BK;

        f32x4 x0, x1, x2, x3;
        bf16x8 b0[4], b1[4], af[4];

        // ================= phase 0: ks=0, mi 0..3 (+ bfrag ks0) =================
#pragma unroll
        for (int ni = 0; ni < 4; ++ni) {
            int r = n0 + ni * 16 + lo;
            b0[ni] = *(const bf16x8*)&wb[r * BK + (((hi4) ^ (r & 7)) << 3)];
        }
#pragma unroll
        for (int mi = 0; mi < 4; ++mi) {
            int r = mi * 16 + lo;
            af[mi] = *(const bf16x8*)&ab[r * BK + (((hi4) ^ (r & 7)) << 3)];
        }
        if (pf) {
            x0 = *(const f32x4*)(asrc);
            x1 = *(const f32x4*)(asrc + 4);
#pragma unroll
            for (int r = 0; r < 2; ++r)
                __builtin_amdgcn_global_load_lds(
                    (const __attribute__((address_space(1))) void*)(wsrc + r * 4096 + tid * 8),
                    (__attribute__((address_space(3))) void*)(wdst + r * 4096 + wid * 512),
                    16, 0, 0);
        }
        PHASE_MFMA(af, b0, 0)
        __builtin_amdgcn_s_barrier();

        // ================= phase 1: ks=0, mi 4..7 =================
#pragma unroll
        for (int mi = 0; mi < 4; ++mi) {
            int r = (mi + 4) * 16 + lo;
            af[mi] = *(const bf16x8*)&ab[r * BK + (((hi4) ^ (r & 7)) << 3)];
        }
        if (pf) {
            x2 = *(const f32x4*)(asrc + 8);
            x3 = *(const f32x4*)(asrc + 12);
#pragma unroll
            for (int r = 2; r < 4; ++r)
                __builtin_amdgcn_global_load_lds(
                    (const __attribute__((address_space(1))) void*)(wsrc + r * 4096 + tid * 8),
                    (__attribute__((address_space(3))) void*)(wdst + r * 4096 + wid * 512),
                    16, 0, 0);
        }
        PHASE_MFMA(af, b0, 4)
        __builtin_amdgcn_s_barrier();

        // ================= phase 2: ks=1, mi 0..3 (+ bfrag ks1, A cvt/write half 0) ====
#pragma unroll
        for (int ni = 0; ni < 4; ++ni) {
            int r = n0 + ni * 16 + lo;
            b1[ni] = *(const bf16x8*)&wb[r * BK + (((4 | hi4) ^ (r & 7)) << 3)];
        }
#pragma unroll
        for (int mi = 0; mi < 4; ++mi) {
            int r = mi * 16 + lo;
            af[mi] = *(const bf16x8*)&ab[r * BK + (((4 | hi4) ^ (r & 7)) << 3)];
        }
        if (pf) {
#pragma unroll
            for (int r = 4; r < 6; ++r)
                __builtin_amdgcn_global_load_lds(
                    (const __attribute__((address_space(1))) void*)(wsrc + r * 4096 + tid * 8),
                    (__attribute__((address_space(3))) void*)(wdst + r * 4096 + wid * 512),
                    16, 0, 0);
            short8 p0;
            p0[0]=f2bf(x0[0]); p0[1]=f2bf(x0[1]); p0[2]=f2bf(x0[2]); p0[3]=f2bf(x0[3]);
            p0[4]=f2bf(x1[0]); p0[5]=f2bf(x1[1]); p0[6]=f2bf(x1[2]); p0[7]=f2bf(x1[3]);
            *(short8*)&adst[arow * BK + (((2 * akc) ^ (arow & 7)) << 3)] = p0;
        }
        PHASE_MFMA(af, b1, 0)
        __builtin_amdgcn_s_barrier();

        // ================= phase 3: ks=1, mi 4..7 (+ A cvt/write half 1, vmcnt drain) ==
#pragma unroll
        for (int mi = 0; mi < 4; ++mi) {
            int r = (mi + 4) * 16 + lo;
            af[mi] = *(const bf16x8*)&ab[r * BK + (((4 | hi4) ^ (r & 7)) << 3)];
        }
        if (pf) {
#pragma unroll
            for (int r = 6; r < 8; ++r)
                __builtin_amdgcn_global_load_lds(
                    (const __attribute__((address_space(1))) void*)(wsrc + r * 4096 + tid * 8),
                    (__attribute__((address_space(3))) void*)(wdst + r * 4096 + wid * 512),
                    16, 0, 0);
            short8 p1;
            p1[0]=f2bf(x2[0]); p1[1]=f2bf(x2[1]); p1[2]=f2bf(x2[2]); p1[3]=f2bf(x2[3]);
            p1[4]=f2bf(x3[0]); p1[5]=f2bf(x3[1]); p1[6]=f2bf(x3[2]); p1[7]=f2bf(x3[3]);
            *(short8*)&adst[arow * BK + (((2 * akc + 1) ^ (arow & 7)) << 3)] = p1;
        }
        PHASE_MFMA(af, b1, 4)
        if (pf) {
            // every wave drains its own global_load_lds before the iter-final barrier
            // so all waves may read each other's staged slices next iteration
            asm volatile("s_waitcnt vmcnt(0)" ::: "memory");
            __builtin_amdgcn_sched_barrier(0);
        }
        __builtin_amdgcn_s_barrier();
    }
#undef PHASE_MFMA

    // ---- epilogue (verified in R1/R2) ----
    {
        float hp[2][4][4];
#pragma unroll
        for (int par = 0; par < 2; ++par)
#pragma unroll
            for (int j = 0; j < 4; ++j) {
                int b = par * 16 + hi4 * 4 + j;
#pragma unroll
                for (int ni = 0; ni < 4; ++ni)
                    hp[par][j][ni] = hidproj[b * H_ + n0 + ni * 16 + lo];
            }
#pragma unroll
        for (int mi = 0; mi < 8; ++mi)
#pragma unroll
            for (int ni = 0; ni < 4; ++ni)
#pragma unroll
                for (int j = 0; j < 4; ++j)
                    acc[mi][ni][j] += hp[mi & 1][j][ni];
    }

    float vh[4];
#pragma unroll
    for (int ni = 0; ni < 4; ++ni) vh[ni] = vvec[n0 + ni * 16 + lo];

    float scp[8][4];
#pragma unroll
    for (int tl = 0; tl < 4; ++tl) {
        const int m0 = tl * 2, m1 = tl * 2 + 1;
#pragma unroll
        for (int ni = 0; ni < 4; ++ni) {
            float mx = -1e30f;
#pragma unroll
            for (int j = 0; j < 4; ++j) {
                mx = fmaxf(mx, acc[m0][ni][j]);
                mx = fmaxf(mx, acc[m1][ni][j]);
            }
            mx = fmaxf(mx, __shfl_xor(mx, 16));
            mx = fmaxf(mx, __shfl_xor(mx, 32));
            float e0[4], e1[4];
            float sum = 0.f;
#pragma unroll
            for (int j = 0; j < 4; ++j) {
                e0[j] = __expf(acc[m0][ni][j] - mx);
                e1[j] = __expf(acc[m1][ni][j] - mx);
                sum += e0[j] + e1[j];
            }
            sum += __shfl_xor(sum, 16);
            sum += __shfl_xor(sum, 32);
            float rs = vh[ni] / sum;
#pragma unroll
            for (int j = 0; j < 4; ++j) {
                if (ni == 0) { scp[m0][j] = e0[j] * rs; scp[m1][j] = e1[j] * rs; }
                else         { scp[m0][j] += e0[j] * rs; scp[m1][j] += e1[j] * rs; }
            }
        }
    }

#pragma unroll
    for (int mi = 0; mi < 8; ++mi)
#pragma unroll
        for (int j = 0; j < 4; ++j) {
            float x = scp[mi][j];
            x += __shfl_xor(x, 1);
            x += __shfl_xor(x, 2);
            x += __shfl_xor(x, 4);
            x += __shfl_xor(x, 8);
            scp[mi][j] = x;
        }

    __syncthreads();
    float* red = (float*)&lds_a[0][0];  // 4 KB reuse
    if (lo == 0) {
#pragma unroll
        for (int mi = 0; mi < 8; ++mi)
#pragma unroll
            for (int j = 0; j < 4; ++j)
                red[wid * 128 + mi * 16 + hi4 * 4 + j] = scp[mi][j];
    }
    __syncthreads();
    if (tid < 128) {
        float s = 0.f;
#pragma unroll
        for (int w = 0; w < 8; ++w) s += red[w * 128 + tid];
        int b  = tid & 31;
        int tl = tid >> 5;
        out[(size_t)b * T_ + (t0 + tl)] = fmaxf(s, 0.f);
    }
}

extern "C" void kernel_launch(void* const* d_in, const int* in_sizes, int n_in,
                              void* d_out, int out_size, void* d_ws, size_t ws_size,
                              hipStream_t stream) {
    const float* hidden = (const float*)d_in[0];
    const float* enc    = (const float*)d_in[1];
    const float* W      = (const float*)d_in[2];
    const float* bias   = (const float*)d_in[3];
    const float* v      = (const float*)d_in[4];
    float* out = (float*)d_out;

    float* hidproj = (float*)d_ws;                    // 64 KB
    short* w2p     = (short*)((char*)d_ws + 65536);   // 512 KB

    prep_w2<<<1024, 256, 0, stream>>>(W, w2p);
    prep_hid<<<dim3(4, 32), 128, 0, stream>>>(hidden, W, bias, hidproj);
    attn_main<<<T_ / TILE_T, NTHREADS, 0, stream>>>(enc, hidproj, w2p, v, out);
}

// Round 4
// 128.586 us; speedup vs baseline: 1.1506x; 1.0950x over previous
//
#include <hip/hip_runtime.h>
#include <hip/hip_bf16.h>

#define B_ 32
#define T_ 4096
#define H_ 512
#define TILE_T 4
#define M_TILE 128   // TILE_T * B_
#define BK 64
#define KSTEPS 8     // H_ / BK
#define NTHREADS 512

typedef __attribute__((ext_vector_type(8))) short short8;
typedef __attribute__((ext_vector_type(8))) __bf16 bf16x8;
typedef __attribute__((ext_vector_type(4))) float f32x4;

__device__ __forceinline__ short f2bf(float f) {
    unsigned u = __builtin_bit_cast(unsigned, f);
    u = (u + 0x7fffu + ((u >> 16) & 1u)) >> 16;
    return (short)u;
}

// ---- prep: W2 -> bf16 fragment-packed for direct global->reg B-frag loads ----
// w2f[c][kk][ks][ni][lane][j]  (c=col block 0..7, kk=kstep 0..7, ks=0..1, ni=0..3)
// lane's frag element j maps to h = c*64+ni*16+(lane&15), k = kk*64+ks*32+(lane>>4)*8+j
__global__ void prep_w2f(const float* __restrict__ W, short* __restrict__ w2f) {
    int idx = blockIdx.x * 256 + threadIdx.x;   // 0 .. 262143
    int j    = idx & 7;
    int lane = (idx >> 3) & 63;
    int ni   = (idx >> 9) & 3;
    int ks   = (idx >> 11) & 1;
    int kk   = (idx >> 12) & 7;
    int c    = (idx >> 15) & 7;
    int h = c * 64 + ni * 16 + (lane & 15);
    int k = kk * 64 + ks * 32 + (lane >> 4) * 8 + j;
    w2f[idx] = f2bf(W[h * (2 * H_) + H_ + k]);
}

// ---- prep: hid_proj[b][h] = hidden[b,:]*W1[h,:] + bias[h] (f32 exact) ----
__global__ void prep_hid(const float* __restrict__ hidden,
                         const float* __restrict__ W,
                         const float* __restrict__ bias,
                         float* __restrict__ hidproj) {
    __shared__ float hrow[H_];
    int b = blockIdx.y;
    int h = blockIdx.x * 128 + threadIdx.x;
    for (int i = threadIdx.x; i < H_; i += 128) hrow[i] = hidden[b * H_ + i];
    __syncthreads();
    const float* wr = W + (size_t)h * (2 * H_);
    float acc = bias[h];
#pragma unroll 4
    for (int k = 0; k < H_; k += 4) {
        acc += hrow[k]     * wr[k];
        acc += hrow[k + 1] * wr[k + 1];
        acc += hrow[k + 2] * wr[k + 2];
        acc += hrow[k + 3] * wr[k + 3];
    }
    hidproj[b * H_ + h] = acc;
}

// ---- main: A-only LDS dbuf, W direct L2->reg, 1 barrier per kstep ----
__global__ __launch_bounds__(NTHREADS, 2)
void attn_main(const float* __restrict__ enc,      // [T][B][H] f32
               const float* __restrict__ hidproj,  // [B][H] f32
               const short* __restrict__ w2f,      // frag-packed bf16 W2
               const float* __restrict__ vvec,     // [H]
               float* __restrict__ out)            // [B][T]
{
    __shared__ __align__(16) short lds_a[2][M_TILE * BK];  // 2 x 16 KB

    const int tid  = threadIdx.x;
    const int lane = tid & 63;
    const int wid  = tid >> 6;
    const int t0   = blockIdx.x * TILE_T;
    const int n0   = wid * 64;
    const int lo   = lane & 15;
    const int hi4  = lane >> 4;

    f32x4 acc[8][4];
#pragma unroll
    for (int i = 0; i < 8; ++i)
#pragma unroll
        for (int j = 0; j < 4; ++j) acc[i][j] = f32x4{0.f, 0.f, 0.f, 0.f};

    // per-wave B-frag stream base: w2f + wid*32768, frag (kk,ks,ni) at ((kk*2+ks)*4+ni)*512 + lane*8
    const short* wbase = w2f + (size_t)wid * 32768 + lane * 8;

    // A staging map: thread -> row (0..127), akc (0..3), 16 f32 each
    const int arow = tid >> 2;
    const int akc  = tid & 3;
    const float* abase = enc + (size_t)(t0 * B_ + arow) * H_ + akc * 16;
    const int aw0 = arow * BK + (((2 * akc)     ^ (arow & 7)) << 3);
    const int aw1 = arow * BK + (((2 * akc + 1) ^ (arow & 7)) << 3);

    // ---- prologue: stage A(0) into lds_a[0] ----
    {
        f32x4 x0 = *(const f32x4*)(abase);
        f32x4 x1 = *(const f32x4*)(abase + 4);
        f32x4 x2 = *(const f32x4*)(abase + 8);
        f32x4 x3 = *(const f32x4*)(abase + 12);
        short8 p0, p1;
        p0[0]=f2bf(x0[0]); p0[1]=f2bf(x0[1]); p0[2]=f2bf(x0[2]); p0[3]=f2bf(x0[3]);
        p0[4]=f2bf(x1[0]); p0[5]=f2bf(x1[1]); p0[6]=f2bf(x1[2]); p0[7]=f2bf(x1[3]);
        p1[0]=f2bf(x2[0]); p1[1]=f2bf(x2[1]); p1[2]=f2bf(x2[2]); p1[3]=f2bf(x2[3]);
        p1[4]=f2bf(x3[0]); p1[5]=f2bf(x3[1]); p1[6]=f2bf(x3[2]); p1[7]=f2bf(x3[3]);
        *(short8*)&lds_a[0][aw0] = p0;
        *(short8*)&lds_a[0][aw1] = p1;
        asm volatile("s_waitcnt lgkmcnt(0)" ::: "memory");
        __builtin_amdgcn_s_barrier();
    }

    for (int kk = 0; kk < KSTEPS; ++kk) {
        const int cur = kk & 1;
        const bool pf = (kk + 1) < KSTEPS;
        const short* __restrict__ ab = &lds_a[cur][0];
        short* __restrict__ adst = &lds_a[cur ^ 1][0];

        // ---- issue B-frag loads for this kstep (L2-resident, coalesced 16B/lane) ----
        bf16x8 b0[4], b1[4];
#pragma unroll
        for (int ni = 0; ni < 4; ++ni)
            b0[ni] = *(const bf16x8*)(wbase + ((kk * 2 + 0) * 4 + ni) * 512);
#pragma unroll
        for (int ni = 0; ni < 4; ++ni)
            b1[ni] = *(const bf16x8*)(wbase + ((kk * 2 + 1) * 4 + ni) * 512);

        // ---- issue A global loads for kstep kk+1 (HBM; hidden under MFMA region) ----
        f32x4 x0, x1, x2, x3;
        if (pf) {
            const float* asrc = abase + (size_t)(kk + 1) * BK;
            x0 = *(const f32x4*)(asrc);
            x1 = *(const f32x4*)(asrc + 4);
            x2 = *(const f32x4*)(asrc + 8);
            x3 = *(const f32x4*)(asrc + 12);
        }

        // ---- ks = 0 ----
        {
            bf16x8 af[4];
#pragma unroll
            for (int mi = 0; mi < 4; ++mi) {
                int r = mi * 16 + lo;
                af[mi] = *(const bf16x8*)&ab[r * BK + ((hi4 ^ (r & 7)) << 3)];
            }
            __builtin_amdgcn_s_setprio(1);
#pragma unroll
            for (int mi = 0; mi < 4; ++mi)
#pragma unroll
                for (int ni = 0; ni < 4; ++ni)
                    acc[mi][ni] = __builtin_amdgcn_mfma_f32_16x16x32_bf16(
                        af[mi], b0[ni], acc[mi][ni], 0, 0, 0);
            __builtin_amdgcn_s_setprio(0);
#pragma unroll
            for (int mi = 0; mi < 4; ++mi) {
                int r = (mi + 4) * 16 + lo;
                af[mi] = *(const bf16x8*)&ab[r * BK + ((hi4 ^ (r & 7)) << 3)];
            }
            __builtin_amdgcn_s_setprio(1);
#pragma unroll
            for (int mi = 0; mi < 4; ++mi)
#pragma unroll
                for (int ni = 0; ni < 4; ++ni)
                    acc[mi + 4][ni] = __builtin_amdgcn_mfma_f32_16x16x32_bf16(
                        af[mi], b0[ni], acc[mi + 4][ni], 0, 0, 0);
            __builtin_amdgcn_s_setprio(0);
        }

        // ---- A(kk+1) half 0: cvt + swizzled ds_write (target dbuf, no sync needed) ----
        if (pf) {
            short8 p0;
            p0[0]=f2bf(x0[0]); p0[1]=f2bf(x0[1]); p0[2]=f2bf(x0[2]); p0[3]=f2bf(x0[3]);
            p0[4]=f2bf(x1[0]); p0[5]=f2bf(x1[1]); p0[6]=f2bf(x1[2]); p0[7]=f2bf(x1[3]);
            *(short8*)&adst[aw0] = p0;
        }

        // ---- ks = 1 ----
        {
            bf16x8 af[4];
#pragma unroll
            for (int mi = 0; mi < 4; ++mi) {
                int r = mi * 16 + lo;
                af[mi] = *(const bf16x8*)&ab[r * BK + (((4 | hi4) ^ (r & 7)) << 3)];
            }
            __builtin_amdgcn_s_setprio(1);
#pragma unroll
            for (int mi = 0; mi < 4; ++mi)
#pragma unroll
                for (int ni = 0; ni < 4; ++ni)
                    acc[mi][ni] = __builtin_amdgcn_mfma_f32_16x16x32_bf16(
                        af[mi], b1[ni], acc[mi][ni], 0, 0, 0);
            __builtin_amdgcn_s_setprio(0);
#pragma unroll
            for (int mi = 0; mi < 4; ++mi) {
                int r = (mi + 4) * 16 + lo;
                af[mi] = *(const bf16x8*)&ab[r * BK + (((4 | hi4) ^ (r & 7)) << 3)];
            }
            __builtin_amdgcn_s_setprio(1);
#pragma unroll
            for (int mi = 0; mi < 4; ++mi)
#pragma unroll
                for (int ni = 0; ni < 4; ++ni)
                    acc[mi + 4][ni] = __builtin_amdgcn_mfma_f32_16x16x32_bf16(
                        af[mi], b1[ni], acc[mi + 4][ni], 0, 0, 0);
            __builtin_amdgcn_s_setprio(0);
        }

        // ---- A(kk+1) half 1 ----
        if (pf) {
            short8 p1;
            p1[0]=f2bf(x2[0]); p1[1]=f2bf(x2[1]); p1[2]=f2bf(x2[2]); p1[3]=f2bf(x2[3]);
            p1[4]=f2bf(x3[0]); p1[5]=f2bf(x3[1]); p1[6]=f2bf(x3[2]); p1[7]=f2bf(x3[3]);
            *(short8*)&adst[aw1] = p1;
        }

        // ---- single barrier per kstep: A(kk+1) visible, everyone advances ----
        asm volatile("s_waitcnt lgkmcnt(0)" ::: "memory");
        __builtin_amdgcn_s_barrier();
    }

    // ---- epilogue (verified R1-R3) ----
    {
        float hp[2][4][4];
#pragma unroll
        for (int par = 0; par < 2; ++par)
#pragma unroll
            for (int j = 0; j < 4; ++j) {
                int b = par * 16 + hi4 * 4 + j;
#pragma unroll
                for (int ni = 0; ni < 4; ++ni)
                    hp[par][j][ni] = hidproj[b * H_ + n0 + ni * 16 + lo];
            }
#pragma unroll
        for (int mi = 0; mi < 8; ++mi)
#pragma unroll
            for (int ni = 0; ni < 4; ++ni)
#pragma unroll
                for (int j = 0; j < 4; ++j)
                    acc[mi][ni][j] += hp[mi & 1][j][ni];
    }

    float vh[4];
#pragma unroll
    for (int ni = 0; ni < 4; ++ni) vh[ni] = vvec[n0 + ni * 16 + lo];

    float scp[8][4];
#pragma unroll
    for (int tl = 0; tl < 4; ++tl) {
        const int m0 = tl * 2, m1 = tl * 2 + 1;
#pragma unroll
        for (int ni = 0; ni < 4; ++ni) {
            float mx = -1e30f;
#pragma unroll
            for (int j = 0; j < 4; ++j) {
                mx = fmaxf(mx, acc[m0][ni][j]);
                mx = fmaxf(mx, acc[m1][ni][j]);
            }
            mx = fmaxf(mx, __shfl_xor(mx, 16));
            mx = fmaxf(mx, __shfl_xor(mx, 32));
            float e0[4], e1[4];
            float sum = 0.f;
#pragma unroll
            for (int j = 0; j < 4; ++j) {
                e0[j] = __expf(acc[m0][ni][j] - mx);
                e1[j] = __expf(acc[m1][ni][j] - mx);
                sum += e0[j] + e1[j];
            }
            sum += __shfl_xor(sum, 16);
            sum += __shfl_xor(sum, 32);
            float rs = vh[ni] / sum;
#pragma unroll
            for (int j = 0; j < 4; ++j) {
                if (ni == 0) { scp[m0][j] = e0[j] * rs; scp[m1][j] = e1[j] * rs; }
                else         { scp[m0][j] += e0[j] * rs; scp[m1][j] += e1[j] * rs; }
            }
        }
    }

#pragma unroll
    for (int mi = 0; mi < 8; ++mi)
#pragma unroll
        for (int j = 0; j < 4; ++j) {
            float x = scp[mi][j];
            x += __shfl_xor(x, 1);
            x += __shfl_xor(x, 2);
            x += __shfl_xor(x, 4);
            x += __shfl_xor(x, 8);
            scp[mi][j] = x;
        }

    __syncthreads();
    float* red = (float*)&lds_a[0][0];
    if (lo == 0) {
#pragma unroll
        for (int mi = 0; mi < 8; ++mi)
#pragma unroll
            for (int j = 0; j < 4; ++j)
                red[wid * 128 + mi * 16 + hi4 * 4 + j] = scp[mi][j];
    }
    __syncthreads();
    if (tid < 128) {
        float s = 0.f;
#pragma unroll
        for (int w = 0; w < 8; ++w) s += red[w * 128 + tid];
        int b  = tid & 31;
        int tl = tid >> 5;
        out[(size_t)b * T_ + (t0 + tl)] = fmaxf(s, 0.f);
    }
}

extern "C" void kernel_launch(void* const* d_in, const int* in_sizes, int n_in,
                              void* d_out, int out_size, void* d_ws, size_t ws_size,
                              hipStream_t stream) {
    const float* hidden = (const float*)d_in[0];
    const float* enc    = (const float*)d_in[1];
    const float* W      = (const float*)d_in[2];
    const float* bias   = (const float*)d_in[3];
    const float* v      = (const float*)d_in[4];
    float* out = (float*)d_out;

    float* hidproj = (float*)d_ws;                    // 64 KB
    short* w2f     = (short*)((char*)d_ws + 65536);   // 512 KB

    prep_w2f<<<1024, 256, 0, stream>>>(W, w2f);
    prep_hid<<<dim3(4, 32), 128, 0, stream>>>(hidden, W, bias, hidproj);
    attn_main<<<T_ / TILE_T, NTHREADS, 0, stream>>>(enc, hidproj, w2f, v, out);
}